// Round 6
// baseline (595.679 us; speedup 1.0000x reference)
//
#include <hip/hip_runtime.h>
#include <math.h>

#define N_NODES 100000
#define N_EDGES 3200000
#define BSHIFT 7
#define BNODES 128                         // nodes per bucket
#define NB 782                             // ceil(N_NODES/128)
#define PLACE_BLOCKS 400
#define G1_S 68                            // gemm1 LDS k-line stride (floats)
#define G1_TILES 1563                      // ceil(N_NODES/64)
#define TILES_A 280                        // gemm tiles fused into stageA
#define TILES_B 600                        // ... stageB
#define TILES_C (G1_TILES - TILES_A - TILES_B)   // 683, stageC
#define BINCNT_BLOCKS 256

typedef float vfloat4 __attribute__((ext_vector_type(4)));  // nontemporal-ok

// ---------------------------------------------------------------------------
// gemm1 tile (R5b body, proven: 142 -> ~80us): one 64-row tile per WAVE.
// Wave-synchronous (no barriers), nontemporal x staging (keeps W1 L1-hot),
// register prefetch of next k-chunk overlapped with compute, 2-way-max LDS
// swizzle. R6: packaged as a device function so tiles can be fused into the
// binning kernels as extra blocks (gemm1 is independent of binning; running
// it concurrently hides ~80us of serial chain).
// ---------------------------------------------------------------------------
__device__ __forceinline__ void gemm1_tile(
    int tile, int lane,
    const float* __restrict__ x, const float* __restrict__ W1,
    float* __restrict__ h, float* __restrict__ xs /* 32*G1_S floats */)
{
    if (tile >= G1_TILES) return;
    const int rbase = tile * 64;

    const int kl4  = (lane & 7) * 4;
    const int rstg = lane >> 3;
    const int swz  = (lane & 7) << 3;
    const int rq   = lane >> 2;
    const int cg   = lane & 3;
    const float4* __restrict__ w4 = (const float4*)W1;

    float4 acc0 = make_float4(0.f, 0.f, 0.f, 0.f);
    float4 acc1 = acc0, acc2 = acc0, acc3 = acc0;

    vfloat4 pre[8];
    #pragma unroll
    for (int i = 0; i < 8; ++i) {
        int rg = rbase + rstg + i * 8;
        pre[i] = (rg < N_NODES)
            ? __builtin_nontemporal_load(
                  (const vfloat4*)(x + (size_t)rg * 512 + kl4))
            : (vfloat4){0.f, 0.f, 0.f, 0.f};
    }

    for (int kc = 0; kc < 512; kc += 32) {
        #pragma unroll
        for (int i = 0; i < 8; ++i) {
            int row = (rstg + i * 8) ^ swz;
            float* p = xs + kl4 * G1_S + row;
            p[0 * G1_S] = pre[i].x;
            p[1 * G1_S] = pre[i].y;
            p[2 * G1_S] = pre[i].z;
            p[3 * G1_S] = pre[i].w;
        }
        if (kc + 32 < 512) {
            #pragma unroll
            for (int i = 0; i < 8; ++i) {
                int rg = rbase + rstg + i * 8;
                pre[i] = (rg < N_NODES)
                    ? __builtin_nontemporal_load(
                          (const vfloat4*)(x + (size_t)rg * 512 + kc + 32 + kl4))
                    : (vfloat4){0.f, 0.f, 0.f, 0.f};
            }
        }

        #pragma unroll
        for (int k4 = 0; k4 < 8; ++k4) {
            const int k0 = k4 * 4;
            const int rr = (rq * 4) ^ (k4 << 3);
            float4 xv0 = *(const float4*)(xs + (k0 + 0) * G1_S + rr);
            float4 xv1 = *(const float4*)(xs + (k0 + 1) * G1_S + rr);
            float4 xv2 = *(const float4*)(xs + (k0 + 2) * G1_S + rr);
            float4 xv3 = *(const float4*)(xs + (k0 + 3) * G1_S + rr);
            float4 wv0 = w4[(kc + k0 + 0) * 4 + cg];
            float4 wv1 = w4[(kc + k0 + 1) * 4 + cg];
            float4 wv2 = w4[(kc + k0 + 2) * 4 + cg];
            float4 wv3 = w4[(kc + k0 + 3) * 4 + cg];

            #define GCN_UPD(xv, wv)                                           \
                acc0.x += (xv).x * (wv).x; acc0.y += (xv).x * (wv).y;         \
                acc0.z += (xv).x * (wv).z; acc0.w += (xv).x * (wv).w;         \
                acc1.x += (xv).y * (wv).x; acc1.y += (xv).y * (wv).y;         \
                acc1.z += (xv).y * (wv).z; acc1.w += (xv).y * (wv).w;         \
                acc2.x += (xv).z * (wv).x; acc2.y += (xv).z * (wv).y;         \
                acc2.z += (xv).z * (wv).z; acc2.w += (xv).z * (wv).w;         \
                acc3.x += (xv).w * (wv).x; acc3.y += (xv).w * (wv).y;         \
                acc3.z += (xv).w * (wv).z; acc3.w += (xv).w * (wv).w;
            GCN_UPD(xv0, wv0)
            GCN_UPD(xv1, wv1)
            GCN_UPD(xv2, wv2)
            GCN_UPD(xv3, wv3)
            #undef GCN_UPD
        }
    }

    {
        int rg = rbase + rq * 4;
        if (rg + 0 < N_NODES) *(float4*)(h + (size_t)(rg + 0) * 16 + cg * 4) = acc0;
        if (rg + 1 < N_NODES) *(float4*)(h + (size_t)(rg + 1) * 16 + cg * 4) = acc1;
        if (rg + 2 < N_NODES) *(float4*)(h + (size_t)(rg + 2) * 16 + cg * 4) = acc2;
        if (rg + 3 < N_NODES) *(float4*)(h + (size_t)(rg + 3) * 16 + cg * 4) = acc3;
    }
}

// ---------------------------------------------------------------------------
// stageA: blocks [0,256) = bin_count; blocks >=256 = gemm1 tiles [0,TILES_A)
// (4 waves/block, each wave one tile). LDS = union -> 34.8KB, 4 blocks/CU.
// ---------------------------------------------------------------------------
union ShA {
    float xs[4][32 * G1_S];
    int hist[NB];
};

__global__ __launch_bounds__(256) void stageA_kernel(
    const float* __restrict__ x, const float* __restrict__ W1,
    float* __restrict__ h,
    const int* __restrict__ ei, int* __restrict__ bucket_cnt)
{
    __shared__ __align__(16) ShA sh;
    const int t = threadIdx.x;

    if (blockIdx.x < BINCNT_BLOCKS) {
        for (int i = t; i < NB; i += 256) sh.hist[i] = 0;
        __syncthreads();
        const int stride = BINCNT_BLOCKS * 256;
        for (int e = blockIdx.x * 256 + t; e < N_EDGES; e += stride)
            atomicAdd(&sh.hist[ei[N_EDGES + e] >> BSHIFT], 1);
        __syncthreads();
        for (int i = t; i < NB; i += 256)
            if (sh.hist[i]) atomicAdd(&bucket_cnt[i], sh.hist[i]);
    } else {
        const int w = t >> 6;
        const int tile = (blockIdx.x - BINCNT_BLOCKS) * 4 + w;
        if (tile < TILES_A)
            gemm1_tile(tile, t & 63, x, W1, h, sh.xs[w]);
    }
}

__global__ __launch_bounds__(1024) void bucket_scan_kernel(
    const int* __restrict__ bucket_cnt, int* __restrict__ bucket_base,
    int* __restrict__ bucket_cursor)
{
    __shared__ int s[1024];
    const int t = threadIdx.x;
    s[t] = (t < NB) ? bucket_cnt[t] : 0;
    __syncthreads();
    for (int off = 1; off < 1024; off <<= 1) {
        int v = (t >= off) ? s[t - off] : 0;
        __syncthreads();
        s[t] += v;
        __syncthreads();
    }
    if (t < NB) {
        int excl = (t == 0) ? 0 : s[t - 1];
        bucket_base[t]   = excl;
        bucket_cursor[t] = excl;
        if (t == NB - 1) bucket_base[NB] = s[t];
    }
}

// ---------------------------------------------------------------------------
// stageB: blocks [0,400) = bin_place; blocks >=400 = gemm1 tiles
// [TILES_A, TILES_A+TILES_B).
// ---------------------------------------------------------------------------
union ShB {
    float xs[4][32 * G1_S];
    struct { int cnt[NB]; int base_off[NB]; int cur[NB]; } p;
};

__global__ __launch_bounds__(256) void stageB_kernel(
    const float* __restrict__ x, const float* __restrict__ W1,
    float* __restrict__ h,
    const int* __restrict__ ei, int* __restrict__ bucket_cursor,
    int* __restrict__ packed)
{
    __shared__ __align__(16) ShB sh;
    const int t = threadIdx.x;

    if (blockIdx.x < PLACE_BLOCKS) {
        const int chunk = (N_EDGES + PLACE_BLOCKS - 1) / PLACE_BLOCKS;   // 8000
        const int cs = blockIdx.x * chunk;
        const int ce = min(cs + chunk, N_EDGES);

        for (int i = t; i < NB; i += 256) { sh.p.cnt[i] = 0; sh.p.cur[i] = 0; }
        __syncthreads();
        for (int e = cs + t; e < ce; e += 256)
            atomicAdd(&sh.p.cnt[ei[N_EDGES + e] >> BSHIFT], 1);
        __syncthreads();
        for (int i = t; i < NB; i += 256)
            sh.p.base_off[i] = sh.p.cnt[i] ? atomicAdd(&bucket_cursor[i], sh.p.cnt[i]) : 0;
        __syncthreads();
        for (int e = cs + t; e < ce; e += 256) {
            int s = ei[e];
            int d = ei[N_EDGES + e];
            int b = d >> BSHIFT;
            int pos = sh.p.base_off[b] + atomicAdd(&sh.p.cur[b], 1);
            packed[pos] = s | ((d & (BNODES - 1)) << 17);
        }
    } else {
        const int w = t >> 6;
        const int tile = TILES_A + (blockIdx.x - PLACE_BLOCKS) * 4 + w;
        if (tile < TILES_A + TILES_B)
            gemm1_tile(tile, t & 63, x, W1, h, sh.xs[w]);
    }
}

// ---------------------------------------------------------------------------
// stageC: blocks [0,782) = csr_sort; blocks >=782 = gemm1 tiles
// [TILES_A+TILES_B, G1_TILES).
// ---------------------------------------------------------------------------
union ShC {
    float xs[4][32 * G1_S];
    struct { int hist[BNODES]; int excl[BNODES]; int cur[BNODES]; int scan[BNODES]; } c;
};

__global__ __launch_bounds__(256) void stageC_kernel(
    const float* __restrict__ x, const float* __restrict__ W1,
    float* __restrict__ h,
    const int* __restrict__ bucket_base, const int* __restrict__ packed,
    int* __restrict__ csr_src, int* __restrict__ row_ptr)
{
    __shared__ __align__(16) ShC sh;
    const int t = threadIdx.x;
    const int b = blockIdx.x;

    if (b < NB) {
        if (t < BNODES) { sh.c.hist[t] = 0; sh.c.cur[t] = 0; }
        __syncthreads();

        const int bs = bucket_base[b];
        const int be = bucket_base[b + 1];
        for (int e = bs + t; e < be; e += 256)
            atomicAdd(&sh.c.hist[packed[e] >> 17], 1);
        __syncthreads();

        if (t < BNODES) sh.c.scan[t] = sh.c.hist[t];
        __syncthreads();
        for (int off = 1; off < BNODES; off <<= 1) {
            int v = (t < BNODES && t >= off) ? sh.c.scan[t - off] : 0;
            __syncthreads();
            if (t < BNODES) sh.c.scan[t] += v;
            __syncthreads();
        }
        if (t < BNODES) {
            int ex = (t == 0) ? 0 : sh.c.scan[t - 1];
            sh.c.excl[t] = ex;
            int g = b * BNODES + t;
            if (g < N_NODES) row_ptr[g] = bs + ex;
        }
        if (b == NB - 1 && t == 0) row_ptr[N_NODES] = N_EDGES;
        __syncthreads();

        for (int e = bs + t; e < be; e += 256) {
            int p  = packed[e];
            int dl = p >> 17;
            int pos = bs + sh.c.excl[dl] + atomicAdd(&sh.c.cur[dl], 1);
            csr_src[pos] = p & 0x1FFFF;
        }
    } else {
        const int w = t >> 6;
        const int tile = TILES_A + TILES_B + (b - NB) * 4 + w;
        if (tile < G1_TILES)
            gemm1_tile(tile, t & 63, x, W1, h, sh.xs[w]);
    }
}

// ---------------------------------------------------------------------------
// gather1: wave per node, 64 lanes = 4 edge slots x 16 channels.
// Epilogue fuses +b1 / relu.
// ---------------------------------------------------------------------------
__global__ __launch_bounds__(256) void gather1_kernel(
    const int* __restrict__ row_ptr, const int* __restrict__ csr_src,
    const float* __restrict__ h, const float* __restrict__ b1,
    float* __restrict__ h1)
{
    const int node = (blockIdx.x * 256 + threadIdx.x) >> 6;
    if (node >= N_NODES) return;
    const int lane = threadIdx.x & 63;
    const int c = lane & 15, slot = lane >> 4;
    const int start = row_ptr[node], end = row_ptr[node + 1];

    float acc = 0.f;
    int e = start;
    for (; e + 16 <= end; e += 16) {
        int s0 = csr_src[e + slot * 4 + 0];
        int s1 = csr_src[e + slot * 4 + 1];
        int s2 = csr_src[e + slot * 4 + 2];
        int s3 = csr_src[e + slot * 4 + 3];
        float v0 = h[s0 * 16 + c];
        float v1 = h[s1 * 16 + c];
        float v2 = h[s2 * 16 + c];
        float v3 = h[s3 * 16 + c];
        acc += (v0 + v1) + (v2 + v3);
    }
    for (; e + 4 <= end; e += 4)
        acc += h[csr_src[e + slot] * 16 + c];
    if (e + slot < end)
        acc += h[csr_src[e + slot] * 16 + c];

    acc += __shfl_xor(acc, 16);
    acc += __shfl_xor(acc, 32);
    if (lane < 16)
        h1[(size_t)node * 16 + c] = fmaxf(acc + b1[c], 0.f);
}

// ---------------------------------------------------------------------------
// gather2 + gemm2 + bias + log_softmax, fully in-wave (shuffle-based).
// ---------------------------------------------------------------------------
__global__ __launch_bounds__(256) void gather2_kernel(
    const int* __restrict__ row_ptr, const int* __restrict__ csr_src,
    const float* __restrict__ h1, const float* __restrict__ W2,
    const float* __restrict__ b2, float* __restrict__ out)
{
    const int node = (blockIdx.x * 256 + threadIdx.x) >> 6;
    if (node >= N_NODES) return;
    const int lane = threadIdx.x & 63;
    const int c = lane & 15, slot = lane >> 4;

    float w2c[16];
    float b2v = 0.f;
    if (lane < 40) {
        b2v = b2[lane];
        #pragma unroll
        for (int k = 0; k < 16; ++k) w2c[k] = W2[k * 40 + lane];
    } else {
        #pragma unroll
        for (int k = 0; k < 16; ++k) w2c[k] = 0.f;
    }

    const int start = row_ptr[node], end = row_ptr[node + 1];
    float acc = 0.f;
    int e = start;
    for (; e + 16 <= end; e += 16) {
        int s0 = csr_src[e + slot * 4 + 0];
        int s1 = csr_src[e + slot * 4 + 1];
        int s2 = csr_src[e + slot * 4 + 2];
        int s3 = csr_src[e + slot * 4 + 3];
        float v0 = h1[s0 * 16 + c];
        float v1 = h1[s1 * 16 + c];
        float v2 = h1[s2 * 16 + c];
        float v3 = h1[s3 * 16 + c];
        acc += (v0 + v1) + (v2 + v3);
    }
    for (; e + 4 <= end; e += 4)
        acc += h1[csr_src[e + slot] * 16 + c];
    if (e + slot < end)
        acc += h1[csr_src[e + slot] * 16 + c];

    acc += __shfl_xor(acc, 16);
    acc += __shfl_xor(acc, 32);

    float z = b2v;
    #pragma unroll
    for (int k = 0; k < 16; ++k)
        z += __shfl(acc, k) * w2c[k];

    float zm = (lane < 40) ? z : -1e30f;
    #pragma unroll
    for (int off = 1; off < 64; off <<= 1)
        zm = fmaxf(zm, __shfl_xor(zm, off));
    float ex = (lane < 40) ? __expf(z - zm) : 0.f;
    float sum = ex;
    #pragma unroll
    for (int off = 1; off < 64; off <<= 1)
        sum += __shfl_xor(sum, off);
    const float lse = zm + __logf(sum);

    if (lane < 40)
        out[(size_t)node * 40 + lane] = z - lse;
}

// ---------------------------------------------------------------------------
extern "C" void kernel_launch(void* const* d_in, const int* in_sizes, int n_in,
                              void* d_out, int out_size, void* d_ws, size_t ws_size,
                              hipStream_t stream)
{
    const float* x  = (const float*)d_in[0];
    const int*   ei = (const int*)d_in[1];
    const float* W1 = (const float*)d_in[2];
    const float* b1 = (const float*)d_in[3];
    const float* W2 = (const float*)d_in[4];
    const float* b2 = (const float*)d_in[5];
    float* out = (float*)d_out;

    // ws (~32.4 MB): h (6.4MB) | csr (12.8MB) | packed (12.8MB, h1 overlays
    // its first 6.4MB after stageC) | rowp | bcnt | bbase | bcur
    float* h      = (float*)d_ws;
    int*   csr    = (int*)(h + (size_t)N_NODES * 16);
    int*   packed = csr + N_EDGES;
    float* h1     = (float*)packed;            // packed dead after stageC
    int*   rowp   = packed + N_EDGES;
    int*   bcnt   = rowp + (N_NODES + 1);
    int*   bbase  = bcnt + NB;
    int*   bcur   = bbase + (NB + 1);

    const int stageA_blocks = BINCNT_BLOCKS + (TILES_A + 3) / 4;     // 326
    const int stageB_blocks = PLACE_BLOCKS + (TILES_B + 3) / 4;      // 550
    const int stageC_blocks = NB + (TILES_C + 3) / 4;                // 953
    const int gather_blocks = (N_NODES + 3) / 4;                     // 25000

    hipMemsetAsync(bcnt, 0, NB * sizeof(int), stream);
    stageA_kernel     <<<stageA_blocks, 256, 0, stream>>>(x, W1, h, ei, bcnt);
    bucket_scan_kernel<<<1, 1024, 0, stream>>>(bcnt, bbase, bcur);
    stageB_kernel     <<<stageB_blocks, 256, 0, stream>>>(x, W1, h, ei, bcur, packed);
    stageC_kernel     <<<stageC_blocks, 256, 0, stream>>>(x, W1, h, bbase, packed, csr, rowp);

    gather1_kernel<<<gather_blocks, 256, 0, stream>>>(rowp, csr, h, b1, h1);
    gather2_kernel<<<gather_blocks, 256, 0, stream>>>(rowp, csr, h1, W2, b2, out);
}